// Round 1
// baseline (3897.344 us; speedup 1.0000x reference)
//
#include <hip/hip_runtime.h>

#define BN_EPS 1e-5f

// ---------------- degree / normalization precompute ----------------

__global__ void deg_init_k(float* __restrict__ deg, int n) {
  int i = blockIdx.x * blockDim.x + threadIdx.x;
  if (i < n) deg[i] = 1.0f;  // self-loop weight
}

__global__ void deg_edges_k(const int* __restrict__ dst, const float* __restrict__ w,
                            float* __restrict__ deg, int e) {
  int i = blockIdx.x * blockDim.x + threadIdx.x;
  if (i < e) unsafeAtomicAdd(&deg[dst[i]], w[i]);
}

__global__ void dinv_k(float* __restrict__ deg, int n) {
  int i = blockIdx.x * blockDim.x + threadIdx.x;
  if (i < n) deg[i] = rsqrtf(deg[i]);  // deg >= 1 always (self-loop)
}

__global__ void coef_k(const int* __restrict__ src, const int* __restrict__ dst,
                       const float* __restrict__ w, const float* __restrict__ dinv,
                       float* __restrict__ coef, int e) {
  int i = blockIdx.x * blockDim.x + threadIdx.x;
  if (i < e) coef[i] = dinv[src[i]] * w[i] * dinv[dst[i]];
}

// ---------------- GEMM: out[r][:] = H[xidx?xidx[r]:r][:] @ W ----------------
// W staged in LDS; each thread computes a float4 of one row's output.

template <int FIN, int FOUT, int ROWS>
__global__ void gemm_k(const float* __restrict__ H, const int* __restrict__ xidx,
                       const float* __restrict__ W, float* __restrict__ out, int n) {
  __shared__ __align__(16) float Ws[FIN * FOUT];
  for (int i = threadIdx.x; i < FIN * FOUT; i += blockDim.x) Ws[i] = W[i];
  __syncthreads();

  constexpr int TPR = FOUT / 4;          // threads per row
  const int lane_j = threadIdx.x % TPR;
  const int rpi = blockDim.x / TPR;      // rows per iteration
  const int r0 = blockIdx.x * ROWS;
  const int rend = min(r0 + ROWS, n);

  for (int r = r0 + threadIdx.x / TPR; r < rend; r += rpi) {
    const int row = xidx ? xidx[r] : r;
    const float4* h4 = (const float4*)(H + (size_t)row * FIN);
    float4 acc = make_float4(0.f, 0.f, 0.f, 0.f);
#pragma unroll
    for (int k4 = 0; k4 < FIN / 4; ++k4) {
      const float4 h = h4[k4];
      const float* wb = &Ws[(k4 * 4) * FOUT + lane_j * 4];
      const float4 w0 = *(const float4*)(wb);
      const float4 w1 = *(const float4*)(wb + FOUT);
      const float4 w2 = *(const float4*)(wb + 2 * FOUT);
      const float4 w3 = *(const float4*)(wb + 3 * FOUT);
      acc.x += h.x * w0.x + h.y * w1.x + h.z * w2.x + h.w * w3.x;
      acc.y += h.x * w0.y + h.y * w1.y + h.z * w2.y + h.w * w3.y;
      acc.z += h.x * w0.z + h.y * w1.z + h.z * w2.z + h.w * w3.z;
      acc.w += h.x * w0.w + h.y * w1.w + h.z * w2.w + h.w * w3.w;
    }
    *(float4*)(out + (size_t)r * FOUT + lane_j * 4) = acc;
  }
}

// ---------------- aggregation ----------------
// agg[i][:] = hW[i][:] * dinv[i]^2 + b[:]   (self-loop + bias)
template <int FOUT>
__global__ void agg_init_k(const float* __restrict__ hW, const float* __restrict__ dinv,
                           const float* __restrict__ b, float* __restrict__ agg, int n) {
  constexpr int TPR = FOUT / 4;
  int gid = blockIdx.x * blockDim.x + threadIdx.x;
  int row = gid / TPR, j = gid % TPR;
  if (row >= n) return;
  float di = dinv[row];
  float c = di * di;
  float4 h = *(const float4*)(hW + (size_t)row * FOUT + j * 4);
  float4 bb = *(const float4*)(b + j * 4);
  float4 o = make_float4(h.x * c + bb.x, h.y * c + bb.y, h.z * c + bb.z, h.w * c + bb.w);
  *(float4*)(agg + (size_t)row * FOUT + j * 4) = o;
}

// agg[dst[e]][:] += hW[src[e]][:] * coef[e]
template <int FOUT>
__global__ void agg_edges_k(const float* __restrict__ hW, const int* __restrict__ src,
                            const int* __restrict__ dst, const float* __restrict__ coef,
                            float* __restrict__ agg, int e) {
  constexpr int TPR = FOUT / 4;
  int gid = blockIdx.x * blockDim.x + threadIdx.x;
  int ed = gid / TPR, j = gid % TPR;
  if (ed >= e) return;
  const float c = coef[ed];
  const int s = src[ed], d = dst[ed];
  const float4 h = *(const float4*)(hW + (size_t)s * FOUT + j * 4);
  float* o = agg + (size_t)d * FOUT + j * 4;
  unsafeAtomicAdd(o + 0, h.x * c);
  unsafeAtomicAdd(o + 1, h.y * c);
  unsafeAtomicAdd(o + 2, h.z * c);
  unsafeAtomicAdd(o + 3, h.w * c);
}

// ---------------- batch norm ----------------

__global__ void zero_k(float* __restrict__ p, int cnt) {
  int i = blockIdx.x * blockDim.x + threadIdx.x;
  if (i < cnt) p[i] = 0.f;
}

template <int FOUT>
__global__ void bn_stats_k(const float* __restrict__ h, float* __restrict__ gsum,
                           float* __restrict__ gsq, int n) {
  constexpr int COPIES = 256 / FOUT;
  __shared__ float ls[256];
  __shared__ float lq[256];
  const int col = threadIdx.x % FOUT;
  const int cp = threadIdx.x / FOUT;
  float s = 0.f, q = 0.f;
  for (int r = blockIdx.x * COPIES + cp; r < n; r += gridDim.x * COPIES) {
    float v = h[(size_t)r * FOUT + col];
    s += v;
    q += v * v;
  }
  ls[threadIdx.x] = s;
  lq[threadIdx.x] = q;
  __syncthreads();
  if (threadIdx.x < FOUT) {
    float ts = 0.f, tq = 0.f;
#pragma unroll
    for (int c = 0; c < COPIES; ++c) {
      ts += ls[c * FOUT + col];
      tq += lq[c * FOUT + col];
    }
    unsafeAtomicAdd(&gsum[col], ts);
    unsafeAtomicAdd(&gsq[col], tq);
  }
}

template <int FOUT>
__global__ void bn_finalize_k(const float* __restrict__ gsum, const float* __restrict__ gsq,
                              const float* __restrict__ g, const float* __restrict__ be,
                              float* __restrict__ scale, float* __restrict__ shift, int n) {
  int c = threadIdx.x;
  if (c >= FOUT) return;
  float inv_n = 1.0f / (float)n;
  float mu = gsum[c] * inv_n;
  float var = gsq[c] * inv_n - mu * mu;
  float sc = g[c] * rsqrtf(var + BN_EPS);
  scale[c] = sc;
  shift[c] = be[c] - mu * sc;
}

template <int FOUT, bool RELU>
__global__ void bn_apply_k(const float* __restrict__ in, const float* __restrict__ scale,
                           const float* __restrict__ shift, float* __restrict__ out, int n) {
  constexpr int TPR = FOUT / 4;
  int gid = blockIdx.x * blockDim.x + threadIdx.x;
  int row = gid / TPR, j = gid % TPR;
  if (row >= n) return;
  float4 v = *(const float4*)(in + (size_t)row * FOUT + j * 4);
  float4 sc = *(const float4*)(scale + j * 4);
  float4 sh = *(const float4*)(shift + j * 4);
  float4 o;
  o.x = v.x * sc.x + sh.x;
  o.y = v.y * sc.y + sh.y;
  o.z = v.z * sc.z + sh.z;
  o.w = v.w * sc.w + sh.w;
  if (RELU) {
    o.x = fmaxf(o.x, 0.f);
    o.y = fmaxf(o.y, 0.f);
    o.z = fmaxf(o.z, 0.f);
    o.w = fmaxf(o.w, 0.f);
  }
  *(float4*)(out + (size_t)row * FOUT + j * 4) = o;
}

// ---------------- launch ----------------

extern "C" void kernel_launch(void* const* d_in, const int* in_sizes, int n_in,
                              void* d_out, int out_size, void* d_ws, size_t ws_size,
                              hipStream_t stream) {
  const int* x = (const int*)d_in[0];
  const int* ei = (const int*)d_in[1];
  const float* w = (const float*)d_in[2];
  const float* emb = (const float*)d_in[3];
  const float* W1 = (const float*)d_in[4];
  const float* b1 = (const float*)d_in[5];
  const float* g1 = (const float*)d_in[6];
  const float* be1 = (const float*)d_in[7];
  const float* W2 = (const float*)d_in[8];
  const float* b2 = (const float*)d_in[9];
  const float* g2 = (const float*)d_in[10];
  const float* be2 = (const float*)d_in[11];
  const float* W3 = (const float*)d_in[12];
  const float* b3 = (const float*)d_in[13];
  const float* g3 = (const float*)d_in[14];
  const float* be3 = (const float*)d_in[15];

  const int n = in_sizes[0];
  const int e = in_sizes[2];
  const int* src = ei;
  const int* dst = ei + e;

  float* ws = (float*)d_ws;
  float* bufA = ws;                            // n*128
  float* bufB = bufA + (size_t)n * 128;        // n*128
  float* dinv = bufB + (size_t)n * 128;        // n   (holds deg first)
  float* coef = dinv + n;                      // e
  float* gsum = coef + e;                      // 128
  float* gsq = gsum + 128;                     // 128
  float* scale = gsq + 128;                    // 128
  float* shift = scale + 128;                  // 128

  const int B = 256;
  dim3 blk(B);

  // graph normalization (shared by all layers)
  deg_init_k<<<(n + B - 1) / B, blk, 0, stream>>>(dinv, n);
  deg_edges_k<<<(e + B - 1) / B, blk, 0, stream>>>(dst, w, dinv, e);
  dinv_k<<<(n + B - 1) / B, blk, 0, stream>>>(dinv, n);
  coef_k<<<(e + B - 1) / B, blk, 0, stream>>>(src, dst, w, dinv, coef, e);

  // ---- layer 1: h0 = emb[x];  hW -> bufA; agg -> bufB; BN+ReLU -> bufA
  gemm_k<128, 128, 64><<<(n + 63) / 64, blk, 0, stream>>>(emb, x, W1, bufA, n);
  agg_init_k<128><<<((size_t)n * 32 + B - 1) / B, blk, 0, stream>>>(bufA, dinv, b1, bufB, n);
  agg_edges_k<128><<<((size_t)e * 32 + B - 1) / B, blk, 0, stream>>>(bufA, src, dst, coef, bufB, e);
  zero_k<<<1, blk, 0, stream>>>(gsum, 256);
  bn_stats_k<128><<<256, blk, 0, stream>>>(bufB, gsum, gsq, n);
  bn_finalize_k<128><<<1, 128, 0, stream>>>(gsum, gsq, g1, be1, scale, shift, n);
  bn_apply_k<128, true><<<((size_t)n * 32 + B - 1) / B, blk, 0, stream>>>(bufB, scale, shift, bufA, n);

  // ---- layer 2: hW -> bufB; agg -> bufA; BN+ReLU -> bufB
  gemm_k<128, 64, 64><<<(n + 63) / 64, blk, 0, stream>>>(bufA, nullptr, W2, bufB, n);
  agg_init_k<64><<<((size_t)n * 16 + B - 1) / B, blk, 0, stream>>>(bufB, dinv, b2, bufA, n);
  agg_edges_k<64><<<((size_t)e * 16 + B - 1) / B, blk, 0, stream>>>(bufB, src, dst, coef, bufA, e);
  zero_k<<<1, blk, 0, stream>>>(gsum, 256);
  bn_stats_k<64><<<256, blk, 0, stream>>>(bufA, gsum, gsq, n);
  bn_finalize_k<64><<<1, 64, 0, stream>>>(gsum, gsq, g2, be2, scale, shift, n);
  bn_apply_k<64, true><<<((size_t)n * 16 + B - 1) / B, blk, 0, stream>>>(bufA, scale, shift, bufB, n);

  // ---- layer 3: hW -> bufA; agg -> bufB; BN -> d_out
  gemm_k<64, 32, 64><<<(n + 63) / 64, blk, 0, stream>>>(bufB, nullptr, W3, bufA, n);
  agg_init_k<32><<<((size_t)n * 8 + B - 1) / B, blk, 0, stream>>>(bufA, dinv, b3, bufB, n);
  agg_edges_k<32><<<((size_t)e * 8 + B - 1) / B, blk, 0, stream>>>(bufA, src, dst, coef, bufB, e);
  zero_k<<<1, blk, 0, stream>>>(gsum, 256);
  bn_stats_k<32><<<256, blk, 0, stream>>>(bufB, gsum, gsq, n);
  bn_finalize_k<32><<<1, 32, 0, stream>>>(gsum, gsq, g3, be3, scale, shift, n);
  bn_apply_k<32, false><<<((size_t)n * 8 + B - 1) / B, blk, 0, stream>>>(bufB, scale, shift, (float*)d_out, n);
}

// Round 2
// 1954.583 us; speedup vs baseline: 1.9940x; 1.9940x over previous
//
#include <hip/hip_runtime.h>

#define BN_EPS 1e-5f

// ---------------- graph preprocessing (CSR by dst) ----------------

__global__ void zero_graph_k(int* __restrict__ cnt, float* __restrict__ degf, int n) {
  int i = blockIdx.x * blockDim.x + threadIdx.x;
  if (i < n) { cnt[i] = 0; degf[i] = 0.f; }
}

__global__ void hist_k(const int* __restrict__ dst, const float* __restrict__ w,
                       int* __restrict__ cnt, float* __restrict__ degf, int e) {
  int i = blockIdx.x * blockDim.x + threadIdx.x;
  if (i < e) {
    int d = dst[i];
    atomicAdd(&cnt[d], 1);
    unsafeAtomicAdd(&degf[d], w[i]);
  }
}

__global__ void dinv_k(float* __restrict__ degf, int n) {
  int i = blockIdx.x * blockDim.x + threadIdx.x;
  if (i < n) degf[i] = rsqrtf(1.0f + degf[i]);  // self-loop weight 1 included
}

// single-block scan: cnt -> rowptr; cursor (aliased onto cnt) = rowptr copy
__global__ void scan_k(int* __restrict__ cnt, int* __restrict__ rowptr, int n) {
  const int T = 1024;
  __shared__ int part[T];
  int t = threadIdx.x;
  int chunk = (n + T - 1) / T;
  int beg = t * chunk, end = min(beg + chunk, n);
  int s = 0;
  for (int i = beg; i < end; ++i) s += cnt[i];
  part[t] = s;
  __syncthreads();
  for (int off = 1; off < T; off <<= 1) {
    int v = (t >= off) ? part[t - off] : 0;
    __syncthreads();
    part[t] += v;
    __syncthreads();
  }
  int base = part[t] - s;  // exclusive prefix for this chunk
  for (int i = beg; i < end; ++i) {
    int c = cnt[i];        // read BEFORE overwriting (cnt aliases cursor)
    rowptr[i] = base;
    cnt[i] = base;         // cursor init
    base += c;
  }
  if (t == T - 1) rowptr[n] = part[T - 1];
}

__global__ void scatter_k(const int* __restrict__ src, const int* __restrict__ dst,
                          const float* __restrict__ w, const float* __restrict__ dinv,
                          int* __restrict__ cursor, int* __restrict__ csr_src,
                          float* __restrict__ csr_coef, int e) {
  int i = blockIdx.x * blockDim.x + threadIdx.x;
  if (i < e) {
    int d = dst[i];
    int s = src[i];
    int pos = atomicAdd(&cursor[d], 1);
    csr_src[pos] = s;
    csr_coef[pos] = dinv[s] * w[i] * dinv[d];
  }
}

// ---------------- GEMM: out[r][:] = f(H[row]) @ W ----------------
// f = identity, or fused BN-apply + ReLU of the previous layer (BNIN).

template <int FIN, int FOUT, int ROWS, bool BNIN>
__global__ void gemm_k(const float* __restrict__ H, const int* __restrict__ xidx,
                       const float* __restrict__ scale, const float* __restrict__ shift,
                       const float* __restrict__ W, float* __restrict__ out, int n) {
  __shared__ __align__(16) float Ws[FIN * FOUT];
  __shared__ float scs[FIN], shs[FIN];
  for (int i = threadIdx.x; i < FIN * FOUT; i += blockDim.x) Ws[i] = W[i];
  if (BNIN) {
    for (int i = threadIdx.x; i < FIN; i += blockDim.x) { scs[i] = scale[i]; shs[i] = shift[i]; }
  }
  __syncthreads();

  constexpr int TPR = FOUT / 4;
  const int lane_j = threadIdx.x % TPR;
  const int rpi = blockDim.x / TPR;
  const int r0 = blockIdx.x * ROWS;
  const int rend = min(r0 + ROWS, n);

  for (int r = r0 + threadIdx.x / TPR; r < rend; r += rpi) {
    const int row = xidx ? xidx[r] : r;
    const float4* h4 = (const float4*)(H + (size_t)row * FIN);
    float4 acc = make_float4(0.f, 0.f, 0.f, 0.f);
#pragma unroll
    for (int k4 = 0; k4 < FIN / 4; ++k4) {
      float4 h = h4[k4];
      if (BNIN) {
        h.x = fmaxf(h.x * scs[k4 * 4 + 0] + shs[k4 * 4 + 0], 0.f);
        h.y = fmaxf(h.y * scs[k4 * 4 + 1] + shs[k4 * 4 + 1], 0.f);
        h.z = fmaxf(h.z * scs[k4 * 4 + 2] + shs[k4 * 4 + 2], 0.f);
        h.w = fmaxf(h.w * scs[k4 * 4 + 3] + shs[k4 * 4 + 3], 0.f);
      }
      const float* wb = &Ws[(k4 * 4) * FOUT + lane_j * 4];
      const float4 w0 = *(const float4*)(wb);
      const float4 w1 = *(const float4*)(wb + FOUT);
      const float4 w2 = *(const float4*)(wb + 2 * FOUT);
      const float4 w3 = *(const float4*)(wb + 3 * FOUT);
      acc.x += h.x * w0.x + h.y * w1.x + h.z * w2.x + h.w * w3.x;
      acc.y += h.x * w0.y + h.y * w1.y + h.z * w2.y + h.w * w3.y;
      acc.z += h.x * w0.z + h.y * w1.z + h.z * w2.z + h.w * w3.z;
      acc.w += h.x * w0.w + h.y * w1.w + h.z * w2.w + h.w * w3.w;
    }
    *(float4*)(out + (size_t)r * FOUT + lane_j * 4) = acc;
  }
}

// ---------------- CSR aggregation (gather-only, no atomics) ----------------
// agg[r] = hW[r]*dinv[r]^2 + b + sum_{e in row r} hW[csr_src[e]] * csr_coef[e]

template <int FOUT>
__global__ void agg_csr_k(const float* __restrict__ hW, const int* __restrict__ rowptr,
                          const int* __restrict__ csr_src, const float* __restrict__ csr_coef,
                          const float* __restrict__ dinv, const float* __restrict__ b,
                          float* __restrict__ agg, int n) {
  constexpr int TPR = FOUT / 4;
  int gid = blockIdx.x * blockDim.x + threadIdx.x;
  int row = gid / TPR, j = gid % TPR;
  if (row >= n) return;

  const float di = dinv[row];
  const float c0 = di * di;
  const float4 h0 = *(const float4*)(hW + (size_t)row * FOUT + j * 4);
  const float4 bb = *(const float4*)(b + j * 4);
  float4 acc = make_float4(h0.x * c0 + bb.x, h0.y * c0 + bb.y,
                           h0.z * c0 + bb.z, h0.w * c0 + bb.w);

  const int e0 = rowptr[row], e1 = rowptr[row + 1];
  for (int e = e0; e < e1; ++e) {
    const int s = csr_src[e];
    const float c = csr_coef[e];
    const float4 v = *(const float4*)(hW + (size_t)s * FOUT + j * 4);
    acc.x += v.x * c;
    acc.y += v.y * c;
    acc.z += v.z * c;
    acc.w += v.w * c;
  }
  *(float4*)(agg + (size_t)row * FOUT + j * 4) = acc;
}

// ---------------- batch norm ----------------

__global__ void zero_k(float* __restrict__ p, int cnt) {
  int i = blockIdx.x * blockDim.x + threadIdx.x;
  if (i < cnt) p[i] = 0.f;
}

template <int FOUT>
__global__ void bn_stats_k(const float* __restrict__ h, float* __restrict__ gsum,
                           float* __restrict__ gsq, int n) {
  constexpr int COPIES = 256 / FOUT;
  __shared__ float ls[256];
  __shared__ float lq[256];
  const int col = threadIdx.x % FOUT;
  const int cp = threadIdx.x / FOUT;
  float s = 0.f, q = 0.f;
  for (int r = blockIdx.x * COPIES + cp; r < n; r += gridDim.x * COPIES) {
    float v = h[(size_t)r * FOUT + col];
    s += v;
    q += v * v;
  }
  ls[threadIdx.x] = s;
  lq[threadIdx.x] = q;
  __syncthreads();
  if (threadIdx.x < FOUT) {
    float ts = 0.f, tq = 0.f;
#pragma unroll
    for (int c = 0; c < COPIES; ++c) {
      ts += ls[c * FOUT + col];
      tq += lq[c * FOUT + col];
    }
    unsafeAtomicAdd(&gsum[col], ts);
    unsafeAtomicAdd(&gsq[col], tq);
  }
}

template <int FOUT>
__global__ void bn_finalize_k(const float* __restrict__ gsum, const float* __restrict__ gsq,
                              const float* __restrict__ g, const float* __restrict__ be,
                              float* __restrict__ scale, float* __restrict__ shift, int n) {
  int c = threadIdx.x;
  if (c >= FOUT) return;
  float inv_n = 1.0f / (float)n;
  float mu = gsum[c] * inv_n;
  float var = gsq[c] * inv_n - mu * mu;
  float sc = g[c] * rsqrtf(var + BN_EPS);
  scale[c] = sc;
  shift[c] = be[c] - mu * sc;
}

template <int FOUT, bool RELU>
__global__ void bn_apply_k(const float* __restrict__ in, const float* __restrict__ scale,
                           const float* __restrict__ shift, float* __restrict__ out, int n) {
  constexpr int TPR = FOUT / 4;
  int gid = blockIdx.x * blockDim.x + threadIdx.x;
  int row = gid / TPR, j = gid % TPR;
  if (row >= n) return;
  float4 v = *(const float4*)(in + (size_t)row * FOUT + j * 4);
  float4 sc = *(const float4*)(scale + j * 4);
  float4 sh = *(const float4*)(shift + j * 4);
  float4 o;
  o.x = v.x * sc.x + sh.x;
  o.y = v.y * sc.y + sh.y;
  o.z = v.z * sc.z + sh.z;
  o.w = v.w * sc.w + sh.w;
  if (RELU) {
    o.x = fmaxf(o.x, 0.f);
    o.y = fmaxf(o.y, 0.f);
    o.z = fmaxf(o.z, 0.f);
    o.w = fmaxf(o.w, 0.f);
  }
  *(float4*)(out + (size_t)row * FOUT + j * 4) = o;
}

// ---------------- launch ----------------

extern "C" void kernel_launch(void* const* d_in, const int* in_sizes, int n_in,
                              void* d_out, int out_size, void* d_ws, size_t ws_size,
                              hipStream_t stream) {
  const int* x = (const int*)d_in[0];
  const int* ei = (const int*)d_in[1];
  const float* w = (const float*)d_in[2];
  const float* emb = (const float*)d_in[3];
  const float* W1 = (const float*)d_in[4];
  const float* b1 = (const float*)d_in[5];
  const float* g1 = (const float*)d_in[6];
  const float* be1 = (const float*)d_in[7];
  const float* W2 = (const float*)d_in[8];
  const float* b2 = (const float*)d_in[9];
  const float* g2 = (const float*)d_in[10];
  const float* be2 = (const float*)d_in[11];
  const float* W3 = (const float*)d_in[12];
  const float* b3 = (const float*)d_in[13];
  const float* g3 = (const float*)d_in[14];
  const float* be3 = (const float*)d_in[15];

  const int n = in_sizes[0];
  const int e = in_sizes[2];
  const int* src = ei;
  const int* dst = ei + e;

  float* ws = (float*)d_ws;
  float* bufA = ws;                              // n*128 (hW)
  float* bufB = bufA + (size_t)n * 128;          // n*128 (agg)
  float* dinv = bufB + (size_t)n * 128;          // n  (deg accum -> dinv in place)
  int* rowptr = (int*)(dinv + n);                // n+1
  int* cursor = rowptr + (n + 1);                // n (doubles as cnt)
  int* csr_src = cursor + n;                     // e
  float* csr_coef = (float*)(csr_src + e);       // e
  float* gsum = csr_coef + e;                    // 128
  float* gsq = gsum + 128;                       // 128
  float* scale = gsq + 128;                      // 128
  float* shift = scale + 128;                    // 128

  const int B = 256;
  dim3 blk(B);

  // CSR build (shared by all layers)
  zero_graph_k<<<(n + B - 1) / B, blk, 0, stream>>>(cursor, dinv, n);
  hist_k<<<(e + B - 1) / B, blk, 0, stream>>>(dst, w, cursor, dinv, e);
  dinv_k<<<(n + B - 1) / B, blk, 0, stream>>>(dinv, n);
  scan_k<<<1, 1024, 0, stream>>>(cursor, rowptr, n);
  scatter_k<<<(e + B - 1) / B, blk, 0, stream>>>(src, dst, w, dinv, cursor, csr_src, csr_coef, e);

  // ---- layer 1: gemm(emb[x]) -> bufA; agg -> bufB; stats
  gemm_k<128, 128, 64, false><<<(n + 63) / 64, blk, 0, stream>>>(emb, x, nullptr, nullptr, W1, bufA, n);
  agg_csr_k<128><<<((size_t)n * 32 + B - 1) / B, blk, 0, stream>>>(bufA, rowptr, csr_src, csr_coef, dinv, b1, bufB, n);
  zero_k<<<1, blk, 0, stream>>>(gsum, 256);
  bn_stats_k<128><<<256, blk, 0, stream>>>(bufB, gsum, gsq, n);
  bn_finalize_k<128><<<1, 128, 0, stream>>>(gsum, gsq, g1, be1, scale, shift, n);

  // ---- layer 2: gemm(BN+ReLU(bufB)) -> bufA; agg -> bufB; stats
  gemm_k<128, 64, 64, true><<<(n + 63) / 64, blk, 0, stream>>>(bufB, nullptr, scale, shift, W2, bufA, n);
  agg_csr_k<64><<<((size_t)n * 16 + B - 1) / B, blk, 0, stream>>>(bufA, rowptr, csr_src, csr_coef, dinv, b2, bufB, n);
  zero_k<<<1, blk, 0, stream>>>(gsum, 256);
  bn_stats_k<64><<<256, blk, 0, stream>>>(bufB, gsum, gsq, n);
  bn_finalize_k<64><<<1, 64, 0, stream>>>(gsum, gsq, g2, be2, scale, shift, n);

  // ---- layer 3: gemm(BN+ReLU(bufB)) -> bufA; agg -> bufB; BN -> d_out
  gemm_k<64, 32, 64, true><<<(n + 63) / 64, blk, 0, stream>>>(bufB, nullptr, scale, shift, W3, bufA, n);
  agg_csr_k<32><<<((size_t)n * 8 + B - 1) / B, blk, 0, stream>>>(bufA, rowptr, csr_src, csr_coef, dinv, b3, bufB, n);
  zero_k<<<1, blk, 0, stream>>>(gsum, 256);
  bn_stats_k<32><<<256, blk, 0, stream>>>(bufB, gsum, gsq, n);
  bn_finalize_k<32><<<1, 32, 0, stream>>>(gsum, gsq, g3, be3, scale, shift, n);
  bn_apply_k<32, false><<<((size_t)n * 8 + B - 1) / B, blk, 0, stream>>>(bufB, scale, shift, (float*)d_out, n);
}